// Round 1
// baseline (296.715 us; speedup 1.0000x reference)
//
#include <hip/hip_runtime.h>

// out[b, :] = opinions_flat[argmax_e weights[b,e], :]
//   where opinions_flat = opinions.reshape(E*B, D), and the argmax index is in
//   [0, E) -- i.e. the gather reads rows 0..15 of opinions[0] (reference quirk).
// E = 16, D = 1024 fixed by the problem; B derived from in_sizes.

__global__ __launch_bounds__(256) void OutputLayer_gather_kernel(
    const float* __restrict__ opinions,  // [E*B, D] flat
    const float* __restrict__ weights,   // [B, E]
    float* __restrict__ out)             // [B, D]
{
    constexpr int E = 16;
    constexpr int D = 1024;

    const int b = blockIdx.x;

    // Per-thread 16-way argmax (first occurrence on ties -> strict >).
    // All 256 threads read the same 64 B; L1 broadcast makes this cheap.
    const float* w = weights + (size_t)b * E;
    float4 w0 = ((const float4*)w)[0];
    float4 w1 = ((const float4*)w)[1];
    float4 w2 = ((const float4*)w)[2];
    float4 w3 = ((const float4*)w)[3];
    float wv[E] = {w0.x, w0.y, w0.z, w0.w, w1.x, w1.y, w1.z, w1.w,
                   w2.x, w2.y, w2.z, w2.w, w3.x, w3.y, w3.z, w3.w};

    int idx = 0;
    float best = wv[0];
    #pragma unroll
    for (int e = 1; e < E; ++e) {
        if (wv[e] > best) { best = wv[e]; idx = e; }
    }

    // Copy row: flat[idx] = opinions + idx*D (idx < 16 < B, so this is
    // within opinions[0]). 256 threads x float4 = 4 KB = one row.
    const float4* src = (const float4*)(opinions + (size_t)idx * D);
    float4* dst = (float4*)(out + (size_t)b * D);
    dst[threadIdx.x] = src[threadIdx.x];
}

extern "C" void kernel_launch(void* const* d_in, const int* in_sizes, int n_in,
                              void* d_out, int out_size, void* d_ws, size_t ws_size,
                              hipStream_t stream) {
    const float* opinions = (const float*)d_in[0];  // [E, B, D] f32
    const float* weights  = (const float*)d_in[1];  // [B, E]    f32
    float* out = (float*)d_out;                     // [B, D]    f32

    constexpr int E = 16;
    const int B = in_sizes[1] / E;  // 4096

    OutputLayer_gather_kernel<<<B, 256, 0, stream>>>(opinions, weights, out);
}